// Round 7
// baseline (654.092 us; speedup 1.0000x reference)
//
#include <hip/hip_runtime.h>
#include <cstdint>

#define N_NODES 100000
#define N_EDGES 1600000
#define H 8
#define D 16
#define HD 128
#define G_GRAPHS 128
#define OUT_DIM 64
#define EPS 1e-3f
#define NEG 0.2f
#define SCAN_BLOCKS 98   // ceil(100000/1024)
#define NBUCK 196        // ceil(100000/512) dst buckets
#define BSHIFT 9         // 512 nodes per bucket
#define BCAP 10240       // per-bucket edge capacity (mean 8192, sigma~90)
#define MT 64            // GEMM rows per tile
#define APAD 136         // LDS A-tile row stride in halfs
#define NTILES 1563      // ceil(100000/64)
#define GEMM_GRID 521    // 521*3 == 1563

typedef __attribute__((ext_vector_type(8))) short bf16x8;
typedef __attribute__((ext_vector_type(4))) float f32x4;
typedef __attribute__((ext_vector_type(8))) unsigned short u16x8;

__device__ __forceinline__ unsigned short f2bf(float x) {
    unsigned u = __float_as_uint(x);
    unsigned r = (u + 0x7FFFu + ((u >> 16) & 1u)) >> 16;  // RTNE
    return (unsigned short)r;
}
__device__ __forceinline__ float bf2f(unsigned short u) {
    return __uint_as_float(((unsigned)u) << 16);
}
__device__ __forceinline__ float plo(unsigned q) {  // low bf16 of pair
    return __uint_as_float(q << 16);
}
__device__ __forceinline__ float phi(unsigned q) {  // high bf16 of pair
    return __uint_as_float(q & 0xFFFF0000u);
}
__device__ __forceinline__ unsigned packbf(float a, float b) {
    return (unsigned)f2bf(a) | ((unsigned)f2bf(b) << 16);
}

// ---- init + weight convert in one kernel --------------------------------
__global__ void init_all(int* __restrict__ bucketCnt, float* __restrict__ pooled,
                         float* __restrict__ sums01, int* __restrict__ cnts,
                         const float* __restrict__ W0, const float* __restrict__ W1,
                         unsigned short* __restrict__ Wt0, unsigned short* __restrict__ Wt1) {
    int tid = blockIdx.x * blockDim.x + threadIdx.x;  // 16384 threads
    if (tid < 256) bucketCnt[tid] = 0;
    if (tid < 512) sums01[tid] = 0.f;
    if (tid < 8) cnts[tid] = 0;
    pooled[tid] = 0.f;                 // exactly G*HD = 16384
    int k = tid >> 7, n = tid & 127;   // Wt[n*128+k] = bf16(W[k*128+n])
    Wt0[n * HD + k] = f2bf(W0[tid]);
    Wt1[n * HD + k] = f2bf(W1[tid]);
}

// ---- CSR build, phase A: bin edges into 196 coarse dst-buckets ----------
__global__ __launch_bounds__(256) void bucket_scatter(const int* __restrict__ src,
                                                      const int* __restrict__ dst,
                                                      int* __restrict__ bucketCnt,
                                                      int2* __restrict__ pairs) {
    __shared__ int hist[NBUCK];
    __shared__ int cur[NBUCK];
    int t = threadIdx.x;
    if (t < NBUCK) hist[t] = 0;
    __syncthreads();
    int base = blockIdx.x * 4096;
    int s[16], d[16];
#pragma unroll
    for (int k = 0; k < 16; ++k) {
        int e = base + t + k * 256;
        if (e < N_EDGES) {
            s[k] = src[e];
            d[k] = dst[e];
            atomicAdd(&hist[d[k] >> BSHIFT], 1);
        } else {
            d[k] = -1;
        }
    }
    __syncthreads();
    if (t < NBUCK) {
        int c = hist[t];
        cur[t] = (c > 0) ? atomicAdd(&bucketCnt[t], c) : 0;
    }
    __syncthreads();
#pragma unroll
    for (int k = 0; k < 16; ++k) {
        if (d[k] >= 0) {
            int b = d[k] >> BSHIFT;
            int slot = atomicAdd(&cur[b], 1);
            pairs[(size_t)b * BCAP + slot] = make_int2(s[k], d[k]);
        }
    }
}

// ---- CSR build, phase A2: per-node degree via per-bucket LDS hist -------
__global__ __launch_bounds__(256) void bucket_count(const int* __restrict__ bucketCnt,
                                                    const int2* __restrict__ pairs,
                                                    int* __restrict__ deg) {
    __shared__ int hist[512];
    int b = blockIdx.x, t = threadIdx.x;
    hist[t] = 0;
    hist[t + 256] = 0;
    __syncthreads();
    int cnt = bucketCnt[b];
    int base0 = b << BSHIFT;
    for (int i = t; i < cnt; i += 256) {
        int2 p = pairs[(size_t)b * BCAP + i];
        atomicAdd(&hist[p.y - base0], 1);
    }
    __syncthreads();
    int n0 = base0 + t, n1 = base0 + t + 256;
    if (n0 < N_NODES) deg[n0] = hist[t];
    if (n1 < N_NODES) deg[n1] = hist[t + 256];
}

// ---- prefix scan of deg -> offs ----------------------------------------
__global__ __launch_bounds__(256) void scan1(const int* __restrict__ deg,
                                             int* __restrict__ offs,
                                             int* __restrict__ blksum) {
    __shared__ int bufA[256], bufB[256];
    int t = threadIdx.x;
    int base = blockIdx.x * 1024;
    int idx = base + t * 4;
    int v[4];
#pragma unroll
    for (int i = 0; i < 4; ++i) v[i] = (idx + i < N_NODES) ? deg[idx + i] : 0;
    int s = v[0] + v[1] + v[2] + v[3];
    bufA[t] = s;
    __syncthreads();
    int* a = bufA; int* b = bufB;
    for (int off = 1; off < 256; off <<= 1) {
        int val = a[t];
        if (t >= off) val += a[t - off];
        b[t] = val;
        __syncthreads();
        int* c = a; a = b; b = c;
    }
    int excl = a[t] - s;
#pragma unroll
    for (int i = 0; i < 4; ++i) {
        if (idx + i < N_NODES) offs[idx + i] = excl;
        excl += v[i];
    }
    if (t == 255) blksum[blockIdx.x] = a[255];
}

__global__ void scan2(const int* __restrict__ blksum, int* __restrict__ blkoff) {
    __shared__ int bufA[128], bufB[128];
    int t = threadIdx.x;  // 128 threads
    int v = (t < SCAN_BLOCKS) ? blksum[t] : 0;
    bufA[t] = v;
    __syncthreads();
    int* a = bufA; int* b = bufB;
    for (int off = 1; off < 128; off <<= 1) {
        int val = a[t];
        if (t >= off) val += a[t - off];
        b[t] = val;
        __syncthreads();
        int* c = a; a = b; b = c;
    }
    if (t < SCAN_BLOCKS) blkoff[t] = a[t] - v;
}

__global__ __launch_bounds__(256) void scan3(int* __restrict__ offs,
                                             const int* __restrict__ blkoff) {
    int base = blockIdx.x * 1024;
    int add = blkoff[blockIdx.x];
#pragma unroll
    for (int i = 0; i < 4; ++i) {
        int idx = base + threadIdx.x + i * 256;
        if (idx < N_NODES) offs[idx] += add;
    }
}

// ---- CSR build, phase B: place edges; LDS rank cursors, dense window ----
__global__ __launch_bounds__(256) void bucket_place(const int* __restrict__ bucketCnt,
                                                    const int2* __restrict__ pairs,
                                                    const int* __restrict__ offs,
                                                    int* __restrict__ csr_src) {
    __shared__ int cur[512];
    int b = blockIdx.x, t = threadIdx.x;
    cur[t] = 0;
    cur[t + 256] = 0;
    __syncthreads();
    int cnt = bucketCnt[b];
    int base0 = b << BSHIFT;
    for (int i = t; i < cnt; i += 256) {
        int2 p = pairs[(size_t)b * BCAP + i];
        int r = atomicAdd(&cur[p.y - base0], 1);
        csr_src[offs[p.y] + r] = p.x;
    }
}

// ---- MFMA GEMM: featb = bf16(X @ W) -------------------------------------
// MODE 0: X fp32. MODE 2: X = gat0 bf16 pairs, apply per-col affine+relu
// (BN fused) during staging using coef[256] = {a[128], b[128]}.
template <int MODE>
__global__ __launch_bounds__(256, 2) void gemm_mfma(const void* __restrict__ Xv,
                                                    const unsigned short* __restrict__ Wt,
                                                    const float* __restrict__ coef,
                                                    unsigned short* __restrict__ Yb,
                                                    int nrows) {
    __shared__ unsigned short As[MT * APAD];
    __shared__ float cf[256];
    int tid = threadIdx.x;
    int wave = tid >> 6, lane = tid & 63;
    int qd = lane >> 4, l16 = lane & 15;

    bf16x8 bfr[8][4];
#pragma unroll
    for (int nt = 0; nt < 8; ++nt)
#pragma unroll
        for (int kb = 0; kb < 4; ++kb)
            bfr[nt][kb] = *(const bf16x8*)&Wt[(nt * 16 + l16) * HD + kb * 32 + qd * 8];

    if (MODE == 2) cf[tid] = coef[tid];

    int srow = tid >> 2, scol = (tid & 3) * 32;  // 4 threads/row, 32 halfs each

    for (int t = blockIdx.x; t < NTILES; t += gridDim.x) {
        int rbase = t * MT;
        __syncthreads();  // covers cf on first iter, As reuse after
        {
            int gr = rbase + srow;
            u16x8 o[4];
            if (gr < nrows) {
                if (MODE == 0) {
                    const float* X = (const float*)Xv;
#pragma unroll
                    for (int i = 0; i < 4; ++i) {
                        float4 va = *(const float4*)&X[(size_t)gr * HD + scol + i * 8];
                        float4 vb = *(const float4*)&X[(size_t)gr * HD + scol + i * 8 + 4];
                        o[i][0] = f2bf(va.x); o[i][1] = f2bf(va.y);
                        o[i][2] = f2bf(va.z); o[i][3] = f2bf(va.w);
                        o[i][4] = f2bf(vb.x); o[i][5] = f2bf(vb.y);
                        o[i][6] = f2bf(vb.z); o[i][7] = f2bf(vb.w);
                    }
                } else {
                    const unsigned* Xp = (const unsigned*)Xv;  // bf16 pairs
#pragma unroll
                    for (int i = 0; i < 4; ++i) {
                        uint4 pr = *(const uint4*)&Xp[(size_t)gr * 64 + (scol >> 1) + i * 4];
                        unsigned pv[4] = {pr.x, pr.y, pr.z, pr.w};
#pragma unroll
                        for (int k = 0; k < 4; ++k) {
                            int c = scol + i * 8 + k * 2;
                            float z0 = fmaf(plo(pv[k]), cf[c], cf[128 + c]);
                            float z1 = fmaf(phi(pv[k]), cf[c + 1], cf[128 + c + 1]);
                            z0 = z0 > 0.f ? z0 : 0.f;
                            z1 = z1 > 0.f ? z1 : 0.f;
                            o[i][2 * k] = f2bf(z0);
                            o[i][2 * k + 1] = f2bf(z1);
                        }
                    }
                }
            } else {
#pragma unroll
                for (int i = 0; i < 4; ++i) o[i] = (u16x8)0;
            }
#pragma unroll
            for (int i = 0; i < 4; ++i)
                *(u16x8*)&As[srow * APAD + scol + i * 8] = o[i];
        }
        __syncthreads();
        f32x4 acc[8];
#pragma unroll
        for (int nt = 0; nt < 8; ++nt) acc[nt] = (f32x4){0.f, 0.f, 0.f, 0.f};
        bf16x8 afr[4];
#pragma unroll
        for (int kb = 0; kb < 4; ++kb)
            afr[kb] = *(const bf16x8*)&As[(wave * 16 + l16) * APAD + kb * 32 + qd * 8];
#pragma unroll
        for (int nt = 0; nt < 8; ++nt)
#pragma unroll
            for (int kb = 0; kb < 4; ++kb)
                acc[nt] = __builtin_amdgcn_mfma_f32_16x16x32_bf16(afr[kb], bfr[nt][kb], acc[nt], 0, 0, 0);
        int orow = rbase + wave * 16 + qd * 4;
        if (orow + 3 < nrows) {
#pragma unroll
            for (int nt = 0; nt < 8; ++nt)
#pragma unroll
                for (int r = 0; r < 4; ++r)
                    Yb[(size_t)(orow + r) * HD + nt * 16 + l16] = f2bf(acc[nt][r]);
        } else {
#pragma unroll
            for (int nt = 0; nt < 8; ++nt)
                for (int r = 0; r < 4; ++r)
                    if (orow + r < nrows)
                        Yb[(size_t)(orow + r) * HD + nt * 16 + l16] = f2bf(acc[nt][r]);
        }
    }
}

// ---- el/er from bf16 feat -----------------------------------------------
__global__ void compute_elr(const unsigned short* __restrict__ featb,
                            const float* __restrict__ al,
                            const float* __restrict__ ar, float* __restrict__ el,
                            float* __restrict__ er) {
    int t = blockIdx.x * blockDim.x + threadIdx.x;
    if (t >= N_NODES * H) return;
    int n = t >> 3, h = t & 7;
    const unsigned* fp = (const unsigned*)&featb[n * HD + h * D];
    const float* ap = &al[h * D];
    const float* bp = &ar[h * D];
    float sl = 0.f, sr = 0.f;
#pragma unroll
    for (int i = 0; i < 8; ++i) {
        unsigned u = fp[i];
        float f0 = plo(u), f1 = phi(u);
        sl += f0 * ap[2 * i] + f1 * ap[2 * i + 1];
        sr += f0 * bp[2 * i] + f1 * bp[2 * i + 1];
    }
    el[t] = sl;
    er[t] = sr;
}

// ---- edge softmax weights, ONE exp per (edge,head), CSR order -----------
// Wave per node; lane = slot*8 + h handles edge (p0+slot), head h.
// wb[p*8+h] bf16: per 8 edges the wave writes 64 contiguous halfs.
__global__ __launch_bounds__(256) void edge_w(const int* __restrict__ offs,
                                              const int* __restrict__ deg,
                                              const int* __restrict__ csr_src,
                                              const float* __restrict__ el,
                                              const float* __restrict__ er,
                                              unsigned short* __restrict__ wb) {
    int node = blockIdx.x * 4 + (threadIdx.x >> 6);
    if (node >= N_NODES) return;
    int lane = threadIdx.x & 63;
    int slot = lane >> 3, h = lane & 7;
    int beg = offs[node];
    int end = beg + deg[node];
    float ern = er[node * H + h];
    for (int p0 = beg; p0 < end; p0 += 8) {
        int idx = p0 + slot;
        bool val = idx < end;
        int s = csr_src[val ? idx : beg];
        float v = el[s * H + h] + ern;
        v = fmaxf(v, NEG * v);
        if (val) wb[(size_t)idx * 8 + h] = f2bf(__expf(v));
    }
}

// ---- per-dst-node GAT gather: no exp, weights streamed from wb ----------
// Lane owns cols 2*lane, 2*lane+1 (head j=lane>>3); dsum = sum of w[e][j].
__global__ __launch_bounds__(256) void gat_node(const int* __restrict__ offs,
                                                const int* __restrict__ deg,
                                                const int* __restrict__ csr_src,
                                                const unsigned short* __restrict__ wb,
                                                const unsigned* __restrict__ featp,
                                                unsigned* __restrict__ gatb) {
    int node = blockIdx.x * 4 + (threadIdx.x >> 6);
    if (node >= N_NODES) return;
    int lane = threadIdx.x & 63;
    int j = lane >> 3;
    int p = offs[node];
    int pend = p + deg[node];
    float dsum = 0.f, accx = 0.f, accy = 0.f;
    for (; p + 8 <= pend; p += 8) {
        int s0 = csr_src[p + 0], s1 = csr_src[p + 1];
        int s2 = csr_src[p + 2], s3 = csr_src[p + 3];
        int s4 = csr_src[p + 4], s5 = csr_src[p + 5];
        int s6 = csr_src[p + 6], s7 = csr_src[p + 7];
        float w0 = bf2f(wb[(size_t)(p + 0) * 8 + j]);
        float w1 = bf2f(wb[(size_t)(p + 1) * 8 + j]);
        float w2 = bf2f(wb[(size_t)(p + 2) * 8 + j]);
        float w3 = bf2f(wb[(size_t)(p + 3) * 8 + j]);
        float w4 = bf2f(wb[(size_t)(p + 4) * 8 + j]);
        float w5 = bf2f(wb[(size_t)(p + 5) * 8 + j]);
        float w6 = bf2f(wb[(size_t)(p + 6) * 8 + j]);
        float w7 = bf2f(wb[(size_t)(p + 7) * 8 + j]);
        unsigned q0 = featp[(size_t)s0 * 64 + lane];
        unsigned q1 = featp[(size_t)s1 * 64 + lane];
        unsigned q2 = featp[(size_t)s2 * 64 + lane];
        unsigned q3 = featp[(size_t)s3 * 64 + lane];
        unsigned q4 = featp[(size_t)s4 * 64 + lane];
        unsigned q5 = featp[(size_t)s5 * 64 + lane];
        unsigned q6 = featp[(size_t)s6 * 64 + lane];
        unsigned q7 = featp[(size_t)s7 * 64 + lane];
        dsum += ((w0 + w1) + (w2 + w3)) + ((w4 + w5) + (w6 + w7));
        accx += w0 * plo(q0); accy += w0 * phi(q0);
        accx += w1 * plo(q1); accy += w1 * phi(q1);
        accx += w2 * plo(q2); accy += w2 * phi(q2);
        accx += w3 * plo(q3); accy += w3 * phi(q3);
        accx += w4 * plo(q4); accy += w4 * phi(q4);
        accx += w5 * plo(q5); accy += w5 * phi(q5);
        accx += w6 * plo(q6); accy += w6 * phi(q6);
        accx += w7 * plo(q7); accy += w7 * phi(q7);
    }
    for (; p < pend; ++p) {
        int s = csr_src[p];
        float w = bf2f(wb[(size_t)p * 8 + j]);
        unsigned q = featp[(size_t)s * 64 + lane];
        dsum += w;
        accx += w * plo(q);
        accy += w * phi(q);
    }
    float invd = dsum > 0.f ? 1.f / dsum : 0.f;
    gatb[(size_t)node * 64 + lane] = packbf(accx * invd, accy * invd);
}

// ---- BN stats + last-block coef emit ------------------------------------
__global__ __launch_bounds__(256) void bn_stats(const unsigned* __restrict__ xb,
                                                float* __restrict__ sums,
                                                int* __restrict__ cnt,
                                                const float* __restrict__ g,
                                                const float* __restrict__ be,
                                                float* __restrict__ coef, int nrows) {
    int cp = threadIdx.x & 63;   // col pair
    int rr = threadIdx.x >> 6;   // 0..3
    float s0 = 0.f, q0 = 0.f, s1 = 0.f, q1 = 0.f;
    for (int r = blockIdx.x * 4 + rr; r < nrows; r += gridDim.x * 4) {
        unsigned u = xb[(size_t)r * 64 + cp];
        float a = plo(u), b = phi(u);
        s0 += a; q0 += a * a;
        s1 += b; q1 += b * b;
    }
    __shared__ float red[4][256];
    red[0][threadIdx.x] = s0;
    red[1][threadIdx.x] = q0;
    red[2][threadIdx.x] = s1;
    red[3][threadIdx.x] = q1;
    __syncthreads();
    if (rr == 0) {
        int c0 = cp * 2, c1 = c0 + 1;
        float ts0 = red[0][cp] + red[0][cp + 64] + red[0][cp + 128] + red[0][cp + 192];
        float tq0 = red[1][cp] + red[1][cp + 64] + red[1][cp + 128] + red[1][cp + 192];
        float ts1 = red[2][cp] + red[2][cp + 64] + red[2][cp + 128] + red[2][cp + 192];
        float tq1 = red[3][cp] + red[3][cp + 64] + red[3][cp + 128] + red[3][cp + 192];
        atomicAdd(&sums[c0], ts0);
        atomicAdd(&sums[128 + c0], tq0);
        atomicAdd(&sums[c1], ts1);
        atomicAdd(&sums[128 + c1], tq1);
    }
    __threadfence();
    __shared__ int last;
    __syncthreads();
    if (threadIdx.x == 0) last = (atomicAdd(cnt, 1) == (int)gridDim.x - 1);
    __syncthreads();
    if (last && threadIdx.x < 128) {
        int c = threadIdx.x;
        float s = atomicAdd(&sums[c], 0.f);        // L2-coherent read
        float q = atomicAdd(&sums[128 + c], 0.f);
        float invN = 1.0f / (float)nrows;
        float mu = s * invN;
        float rs = rsqrtf(q * invN - mu * mu + EPS);
        float a = rs * g[c];
        coef[c] = a;
        coef[128 + c] = be[c] - mu * a;
    }
}

// ---- fused epilogue: bn1+relu + recompute h1 + residual + sum-pool ------
__global__ __launch_bounds__(256) void bn_pool(const unsigned* __restrict__ gat0p,
                                               const unsigned* __restrict__ gat1p,
                                               const float* __restrict__ coef0,
                                               const float* __restrict__ coef1,
                                               const int* __restrict__ gid,
                                               float* __restrict__ pooled) {
    int cp = threadIdx.x & 63;
    int rr = threadIdx.x >> 6;
    int c0 = cp * 2, c1 = c0 + 1;
    float a00 = coef0[c0], a01 = coef0[c1], b00 = coef0[128 + c0], b01 = coef0[128 + c1];
    float a10 = coef1[c0], a11 = coef1[c1], b10 = coef1[128 + c0], b11 = coef1[128 + c1];
    int r0 = blockIdx.x * 512;
    int rend = r0 + 512 < N_NODES ? r0 + 512 : N_NODES;
    int r = r0 + rr;
    if (r >= rend) return;
    float acc0 = 0.f, acc1 = 0.f;
    int cur = gid[r];
    for (; r < rend; r += 4) {
        int gg = gid[r];
        if (gg != cur) {
            atomicAdd(&pooled[cur * HD + c0], acc0);
            atomicAdd(&pooled[cur * HD + c1], acc1);
            acc0 = acc1 = 0.f;
            cur = gg;
        }
        unsigned u1 = gat1p[(size_t)r * 64 + cp];
        unsigned u0 = gat0p[(size_t)r * 64 + cp];
        float z0 = fmaf(plo(u1), a10, b10);
        float z1 = fmaf(phi(u1), a11, b11);
        float h0 = fmaf(plo(u0), a00, b00);
        float h1v = fmaf(phi(u0), a01, b01);
        z0 = z0 > 0.f ? z0 : 0.f;
        z1 = z1 > 0.f ? z1 : 0.f;
        h0 = h0 > 0.f ? h0 : 0.f;
        h1v = h1v > 0.f ? h1v : 0.f;
        acc0 += z0 + h0;
        acc1 += z1 + h1v;
    }
    atomicAdd(&pooled[cur * HD + c0], acc0);
    atomicAdd(&pooled[cur * HD + c1], acc1);
}

// ---- masked prediction head ---------------------------------------------
__global__ void pred_kernel(const float* __restrict__ pooled, const float* __restrict__ W,
                            const float* __restrict__ b, const float* __restrict__ mask,
                            float* __restrict__ out) {
    int t = blockIdx.x * blockDim.x + threadIdx.x;
    if (t >= G_GRAPHS * OUT_DIM) return;
    int g = t >> 6, o = t & 63;
    float acc = b[o];
#pragma unroll 4
    for (int c = 0; c < HD; ++c) {
        float m = mask[o * HD + c] > 0.5f ? 1.f : 0.f;
        acc += pooled[g * HD + c] * W[o * HD + c] * m;
    }
    out[t] = acc;
}

extern "C" void kernel_launch(void* const* d_in, const int* in_sizes, int n_in,
                              void* d_out, int out_size, void* d_ws, size_t ws_size,
                              hipStream_t stream) {
    const float* h   = (const float*)d_in[0];
    const int*   src = (const int*)d_in[1];
    const int*   dst = (const int*)d_in[2];
    const int*   gid = (const int*)d_in[3];
    const float* W0  = (const float*)d_in[4];
    const float* al0 = (const float*)d_in[5];
    const float* ar0 = (const float*)d_in[6];
    // d_in[7] = b0 — BN shift-invariance: bias cancels exactly
    const float* g0  = (const float*)d_in[8];
    const float* be0 = (const float*)d_in[9];
    const float* W1  = (const float*)d_in[10];
    const float* al1 = (const float*)d_in[11];
    const float* ar1 = (const float*)d_in[12];
    // d_in[13] = b1 — cancels
    const float* g1  = (const float*)d_in[14];
    const float* be1 = (const float*)d_in[15];
    const float* pW  = (const float*)d_in[16];
    const float* pb  = (const float*)d_in[17];
    const float* msk = (const float*)d_in[18];
    float* out = (float*)d_out;

    // workspace layout (4B units)
    unsigned* gat0p = (unsigned*)d_ws;                              // [N,64] bf16 pairs
    unsigned* gat1p = gat0p + (size_t)N_NODES * 64;                 // [N,64] bf16 pairs
    unsigned short* featb = (unsigned short*)(gat1p + (size_t)N_NODES * 64); // [N,128] bf16
    unsigned short* wb = featb + (size_t)N_NODES * HD;              // [E,8] bf16
    float* el   = (float*)(wb + (size_t)N_EDGES * 8);               // [N,8]
    float* er   = el + (size_t)N_NODES * H;                         // [N,8]
    int*   offs = (int*)(er + (size_t)N_NODES * H);                 // [N]
    int*   deg  = offs + N_NODES;                                   // [N]
    int*   csr_src = deg + N_NODES;                                 // [E]
    int*   bucketCnt = csr_src + N_EDGES;                           // [256]
    int*   blksum = bucketCnt + 256;                                // [128]
    int*   blkoff = blksum + 128;                                   // [128]
    int*   cnts   = blkoff + 128;                                   // [8]
    float* sums0  = (float*)(cnts + 8);                             // [256]
    float* sums1  = sums0 + 256;                                    // [256]
    float* coef0  = sums1 + 256;                                    // [256]
    float* coef1  = coef0 + 256;                                    // [256]
    float* pooled = coef1 + 256;                                    // [128,128]
    unsigned short* wt0 = (unsigned short*)(pooled + G_GRAPHS * HD);// [128,128] bf16
    unsigned short* wt1 = wt0 + HD * HD;                            // [128,128] bf16
    // pairs aliased over gat1p (16.05 MB < 25.6 MB; dead before L1 gat_node)
    int2* pairs = (int2*)gat1p;

    const int TB = 256;
    dim3 blk(TB);
    int elr_blocks  = (N_NODES * H + TB - 1) / TB;
    int bsc_blocks  = (N_EDGES + 4095) / 4096;
    int node_blocks = (N_NODES + 3) / 4;
    int bnp_blocks  = (N_NODES + 511) / 512;

    // ---------------- CSR build + init + weight convert ----------------
    init_all<<<64, blk, 0, stream>>>(bucketCnt, pooled, sums0, cnts, W0, W1, wt0, wt1);
    bucket_scatter<<<bsc_blocks, blk, 0, stream>>>(src, dst, bucketCnt, pairs);
    bucket_count<<<NBUCK, blk, 0, stream>>>(bucketCnt, pairs, deg);
    scan1<<<SCAN_BLOCKS, blk, 0, stream>>>(deg, offs, blksum);
    scan2<<<1, 128, 0, stream>>>(blksum, blkoff);
    scan3<<<SCAN_BLOCKS, blk, 0, stream>>>(offs, blkoff);
    bucket_place<<<NBUCK, blk, 0, stream>>>(bucketCnt, pairs, offs, csr_src);

    // ---------------- layer 0 ----------------
    gemm_mfma<0><<<GEMM_GRID, blk, 0, stream>>>(h, wt0, nullptr, featb, N_NODES);
    compute_elr<<<elr_blocks, blk, 0, stream>>>(featb, al0, ar0, el, er);
    edge_w<<<node_blocks, blk, 0, stream>>>(offs, deg, csr_src, el, er, wb);
    gat_node<<<node_blocks, blk, 0, stream>>>(offs, deg, csr_src, wb,
                                              (const unsigned*)featb, gat0p);
    bn_stats<<<512, blk, 0, stream>>>(gat0p, sums0, &cnts[0], g0, be0, coef0, N_NODES);

    // ---------------- layer 1 (BN0+ReLU fused into GEMM staging) --------
    gemm_mfma<2><<<GEMM_GRID, blk, 0, stream>>>(gat0p, wt1, coef0, featb, N_NODES);
    compute_elr<<<elr_blocks, blk, 0, stream>>>(featb, al1, ar1, el, er);
    edge_w<<<node_blocks, blk, 0, stream>>>(offs, deg, csr_src, el, er, wb);
    gat_node<<<node_blocks, blk, 0, stream>>>(offs, deg, csr_src, wb,
                                              (const unsigned*)featb, gat1p);
    bn_stats<<<512, blk, 0, stream>>>(gat1p, sums1, &cnts[1], g1, be1, coef1, N_NODES);

    // ---------------- fused epilogue + head ----------------
    bn_pool<<<bnp_blocks, blk, 0, stream>>>(gat0p, gat1p, coef0, coef1, gid, pooled);
    pred_kernel<<<(G_GRAPHS * OUT_DIM + TB - 1) / TB, blk, 0, stream>>>(pooled, pW, pb, msk, out);
}

// Round 9
// 593.940 us; speedup vs baseline: 1.1013x; 1.1013x over previous
//
#include <hip/hip_runtime.h>
#include <cstdint>

#define N_NODES 100000
#define N_EDGES 1600000
#define H 8
#define D 16
#define HD 128
#define G_GRAPHS 128
#define OUT_DIM 64
#define EPS 1e-3f
#define NEG 0.2f
#define SCAN_BLOCKS 98   // ceil(100000/1024)
#define NBUCK 196        // ceil(100000/512) dst buckets
#define BSHIFT 9         // 512 nodes per bucket
#define BCAP 10240       // per-bucket edge capacity (mean 8192, sigma~90)
#define MT 64            // GEMM rows per tile
#define APAD 136         // LDS A-tile row stride in halfs
#define NTILES 1563      // ceil(100000/64)
#define GEMM_GRID 521    // 521*3 == 1563

typedef __attribute__((ext_vector_type(8))) short bf16x8;
typedef __attribute__((ext_vector_type(4))) float f32x4;
typedef __attribute__((ext_vector_type(8))) unsigned short u16x8;

__device__ __forceinline__ unsigned short f2bf(float x) {
    unsigned u = __float_as_uint(x);
    unsigned r = (u + 0x7FFFu + ((u >> 16) & 1u)) >> 16;  // RTNE
    return (unsigned short)r;
}
__device__ __forceinline__ float bf2f(unsigned short u) {
    return __uint_as_float(((unsigned)u) << 16);
}
__device__ __forceinline__ float plo(unsigned q) {  // low bf16 of pair
    return __uint_as_float(q << 16);
}
__device__ __forceinline__ float phi(unsigned q) {  // high bf16 of pair
    return __uint_as_float(q & 0xFFFF0000u);
}
__device__ __forceinline__ unsigned packbf(float a, float b) {
    return (unsigned)f2bf(a) | ((unsigned)f2bf(b) << 16);
}

// ---- init + weight/attn convert in one kernel ---------------------------
// Aeff[n][k] = sum_d W[k][h*16+d] * a[h*16+d]  (h = n&7; a = al for n<8,
// ar for n>=8). Then el/er = X @ Aeff  ==  (X@W) @ blockdiag(al|ar).
__global__ void init_all(int* __restrict__ bucketCnt, float* __restrict__ pooled,
                         float* __restrict__ sums01, int* __restrict__ cnts,
                         const float* __restrict__ W0, const float* __restrict__ W1,
                         unsigned short* __restrict__ Wt0, unsigned short* __restrict__ Wt1,
                         const float* __restrict__ al0, const float* __restrict__ ar0,
                         const float* __restrict__ al1, const float* __restrict__ ar1,
                         unsigned short* __restrict__ Alr0, unsigned short* __restrict__ Alr1) {
    int tid = blockIdx.x * blockDim.x + threadIdx.x;  // 16384 threads
    if (tid < 256) bucketCnt[tid] = 0;
    if (tid < 512) sums01[tid] = 0.f;
    if (tid < 8) cnts[tid] = 0;
    pooled[tid] = 0.f;                 // exactly G*HD = 16384
    int k = tid >> 7, n = tid & 127;   // Wt[n*128+k] = bf16(W[k*128+n])
    Wt0[n * HD + k] = f2bf(W0[tid]);
    Wt1[n * HD + k] = f2bf(W1[tid]);
    if (tid < 2048) {
        int nn = tid >> 7, kk = tid & 127;   // Alr[nn*128+kk]
        int hh = nn & 7;
        const float* a0 = (nn < 8) ? al0 : ar0;
        const float* a1 = (nn < 8) ? al1 : ar1;
        float s0 = 0.f, s1 = 0.f;
#pragma unroll
        for (int d = 0; d < 16; ++d) {
            int j = hh * 16 + d;
            s0 += W0[kk * HD + j] * a0[j];
            s1 += W1[kk * HD + j] * a1[j];
        }
        Alr0[tid] = f2bf(s0);
        Alr1[tid] = f2bf(s1);
    }
}

// ---- CSR build, phase A: bin edges into 196 coarse dst-buckets ----------
// Packed entry: (dst&511)<<17 | src  (src<2^17, local dst<2^9)
__global__ __launch_bounds__(256) void bucket_scatter(const int* __restrict__ src,
                                                      const int* __restrict__ dst,
                                                      int* __restrict__ bucketCnt,
                                                      int* __restrict__ pairs) {
    __shared__ int hist[NBUCK];
    __shared__ int cur[NBUCK];
    int t = threadIdx.x;
    if (t < NBUCK) hist[t] = 0;
    __syncthreads();
    int base = blockIdx.x * 4096;
    int s[16], d[16];
#pragma unroll
    for (int k = 0; k < 16; ++k) {
        int e = base + t + k * 256;
        if (e < N_EDGES) {
            s[k] = src[e];
            d[k] = dst[e];
            atomicAdd(&hist[d[k] >> BSHIFT], 1);
        } else {
            d[k] = -1;
        }
    }
    __syncthreads();
    if (t < NBUCK) {
        int c = hist[t];
        cur[t] = (c > 0) ? atomicAdd(&bucketCnt[t], c) : 0;
    }
    __syncthreads();
#pragma unroll
    for (int k = 0; k < 16; ++k) {
        if (d[k] >= 0) {
            int b = d[k] >> BSHIFT;
            int slot = atomicAdd(&cur[b], 1);
            pairs[(size_t)b * BCAP + slot] = ((d[k] & 511) << 17) | s[k];
        }
    }
}

// ---- CSR build, phase A2: per-node degree via per-bucket LDS hist -------
__global__ __launch_bounds__(256) void bucket_count(const int* __restrict__ bucketCnt,
                                                    const int* __restrict__ pairs,
                                                    int* __restrict__ deg) {
    __shared__ int hist[512];
    int b = blockIdx.x, t = threadIdx.x;
    hist[t] = 0;
    hist[t + 256] = 0;
    __syncthreads();
    int cnt = bucketCnt[b];
    int base0 = b << BSHIFT;
    for (int i = t; i < cnt; i += 256) {
        int v = pairs[(size_t)b * BCAP + i];
        atomicAdd(&hist[v >> 17], 1);
    }
    __syncthreads();
    int n0 = base0 + t, n1 = base0 + t + 256;
    if (n0 < N_NODES) deg[n0] = hist[t];
    if (n1 < N_NODES) deg[n1] = hist[t + 256];
}

// ---- prefix scan of deg -> offs ----------------------------------------
__global__ __launch_bounds__(256) void scan1(const int* __restrict__ deg,
                                             int* __restrict__ offs,
                                             int* __restrict__ blksum) {
    __shared__ int bufA[256], bufB[256];
    int t = threadIdx.x;
    int base = blockIdx.x * 1024;
    int idx = base + t * 4;
    int v[4];
#pragma unroll
    for (int i = 0; i < 4; ++i) v[i] = (idx + i < N_NODES) ? deg[idx + i] : 0;
    int s = v[0] + v[1] + v[2] + v[3];
    bufA[t] = s;
    __syncthreads();
    int* a = bufA; int* b = bufB;
    for (int off = 1; off < 256; off <<= 1) {
        int val = a[t];
        if (t >= off) val += a[t - off];
        b[t] = val;
        __syncthreads();
        int* c = a; a = b; b = c;
    }
    int excl = a[t] - s;
#pragma unroll
    for (int i = 0; i < 4; ++i) {
        if (idx + i < N_NODES) offs[idx + i] = excl;
        excl += v[i];
    }
    if (t == 255) blksum[blockIdx.x] = a[255];
}

__global__ void scan2(const int* __restrict__ blksum, int* __restrict__ blkoff) {
    __shared__ int bufA[128], bufB[128];
    int t = threadIdx.x;  // 128 threads
    int v = (t < SCAN_BLOCKS) ? blksum[t] : 0;
    bufA[t] = v;
    __syncthreads();
    int* a = bufA; int* b = bufB;
    for (int off = 1; off < 128; off <<= 1) {
        int val = a[t];
        if (t >= off) val += a[t - off];
        b[t] = val;
        __syncthreads();
        int* c = a; a = b; b = c;
    }
    if (t < SCAN_BLOCKS) blkoff[t] = a[t] - v;
}

__global__ __launch_bounds__(256) void scan3(int* __restrict__ offs,
                                             const int* __restrict__ blkoff) {
    int base = blockIdx.x * 1024;
    int add = blkoff[blockIdx.x];
#pragma unroll
    for (int i = 0; i < 4; ++i) {
        int idx = base + threadIdx.x + i * 256;
        if (idx < N_NODES) offs[idx] += add;
    }
}

// ---- CSR build, phase B: place edges; LDS rank cursors ------------------
__global__ __launch_bounds__(256) void bucket_place(const int* __restrict__ bucketCnt,
                                                    const int* __restrict__ pairs,
                                                    const int* __restrict__ offs,
                                                    int* __restrict__ csr_src) {
    __shared__ int cur[512];
    int b = blockIdx.x, t = threadIdx.x;
    cur[t] = 0;
    cur[t + 256] = 0;
    __syncthreads();
    int cnt = bucketCnt[b];
    int base0 = b << BSHIFT;
    for (int i = t; i < cnt; i += 256) {
        int v = pairs[(size_t)b * BCAP + i];
        int local = v >> 17;
        int r = atomicAdd(&cur[local], 1);
        csr_src[offs[base0 + local] + r] = v & 0x1FFFF;
    }
}

// ---- MFMA GEMM + fused el/er: featb = bf16(X@W); el/er = X@Aeff ---------
// MODE 0: X fp32. MODE 2: X = gat0 bf16 pairs + per-col affine+relu (BN0).
template <int MODE>
__global__ __launch_bounds__(256, 2) void gemm_mfma(const void* __restrict__ Xv,
                                                    const unsigned short* __restrict__ Wt,
                                                    const unsigned short* __restrict__ Alr,
                                                    const float* __restrict__ coef,
                                                    unsigned short* __restrict__ Yb,
                                                    float* __restrict__ el,
                                                    float* __restrict__ er,
                                                    int nrows) {
    __shared__ unsigned short As[MT * APAD];
    __shared__ float cf[256];
    int tid = threadIdx.x;
    int wave = tid >> 6, lane = tid & 63;
    int qd = lane >> 4, l16 = lane & 15;

    bf16x8 bfr[8][4];
#pragma unroll
    for (int nt = 0; nt < 8; ++nt)
#pragma unroll
        for (int kb = 0; kb < 4; ++kb)
            bfr[nt][kb] = *(const bf16x8*)&Wt[(nt * 16 + l16) * HD + kb * 32 + qd * 8];
    bf16x8 efr[4];
#pragma unroll
    for (int kb = 0; kb < 4; ++kb)
        efr[kb] = *(const bf16x8*)&Alr[l16 * HD + kb * 32 + qd * 8];

    if (MODE == 2) cf[tid] = coef[tid];

    int srow = tid >> 2, scol = (tid & 3) * 32;  // 4 threads/row, 32 halfs each

    for (int t = blockIdx.x; t < NTILES; t += gridDim.x) {
        int rbase = t * MT;
        __syncthreads();  // covers cf on first iter, As reuse after
        {
            int gr = rbase + srow;
            u16x8 o[4];
            if (gr < nrows) {
                if (MODE == 0) {
                    const float* X = (const float*)Xv;
#pragma unroll
                    for (int i = 0; i < 4; ++i) {
                        float4 va = *(const float4*)&X[(size_t)gr * HD + scol + i * 8];
                        float4 vb = *(const float4*)&X[(size_t)gr * HD + scol + i * 8 + 4];
                        o[i][0] = f2bf(va.x); o[i][1] = f2bf(va.y);
                        o[i][2] = f2bf(va.z); o[i][3] = f2bf(va.w);
                        o[i][4] = f2bf(vb.x); o[i][5] = f2bf(vb.y);
                        o[i][6] = f2bf(vb.z); o[i][7] = f2bf(vb.w);
                    }
                } else {
                    const unsigned* Xp = (const unsigned*)Xv;  // bf16 pairs
#pragma unroll
                    for (int i = 0; i < 4; ++i) {
                        uint4 pr = *(const uint4*)&Xp[(size_t)gr * 64 + (scol >> 1) + i * 4];
                        unsigned pv[4] = {pr.x, pr.y, pr.z, pr.w};
#pragma unroll
                        for (int k = 0; k < 4; ++k) {
                            int c = scol + i * 8 + k * 2;
                            float z0 = fmaf(plo(pv[k]), cf[c], cf[128 + c]);
                            float z1 = fmaf(phi(pv[k]), cf[c + 1], cf[128 + c + 1]);
                            z0 = z0 > 0.f ? z0 : 0.f;
                            z1 = z1 > 0.f ? z1 : 0.f;
                            o[i][2 * k] = f2bf(z0);
                            o[i][2 * k + 1] = f2bf(z1);
                        }
                    }
                }
            } else {
#pragma unroll
                for (int i = 0; i < 4; ++i) o[i] = (u16x8)0;
            }
#pragma unroll
            for (int i = 0; i < 4; ++i)
                *(u16x8*)&As[srow * APAD + scol + i * 8] = o[i];
        }
        __syncthreads();
        f32x4 acc[8];
        f32x4 acce = (f32x4){0.f, 0.f, 0.f, 0.f};
#pragma unroll
        for (int nt = 0; nt < 8; ++nt) acc[nt] = (f32x4){0.f, 0.f, 0.f, 0.f};
        bf16x8 afr[4];
#pragma unroll
        for (int kb = 0; kb < 4; ++kb)
            afr[kb] = *(const bf16x8*)&As[(wave * 16 + l16) * APAD + kb * 32 + qd * 8];
#pragma unroll
        for (int nt = 0; nt < 8; ++nt)
#pragma unroll
            for (int kb = 0; kb < 4; ++kb)
                acc[nt] = __builtin_amdgcn_mfma_f32_16x16x32_bf16(afr[kb], bfr[nt][kb], acc[nt], 0, 0, 0);
#pragma unroll
        for (int kb = 0; kb < 4; ++kb)
            acce = __builtin_amdgcn_mfma_f32_16x16x32_bf16(afr[kb], efr[kb], acce, 0, 0, 0);
        int orow = rbase + wave * 16 + qd * 4;
        if (orow + 3 < nrows) {
#pragma unroll
            for (int nt = 0; nt < 8; ++nt)
#pragma unroll
                for (int r = 0; r < 4; ++r)
                    Yb[(size_t)(orow + r) * HD + nt * 16 + l16] = f2bf(acc[nt][r]);
#pragma unroll
            for (int r = 0; r < 4; ++r) {
                if (l16 < 8) el[(size_t)(orow + r) * 8 + l16] = acce[r];
                else         er[(size_t)(orow + r) * 8 + (l16 - 8)] = acce[r];
            }
        } else {
#pragma unroll
            for (int nt = 0; nt < 8; ++nt)
                for (int r = 0; r < 4; ++r)
                    if (orow + r < nrows)
                        Yb[(size_t)(orow + r) * HD + nt * 16 + l16] = f2bf(acc[nt][r]);
            for (int r = 0; r < 4; ++r) {
                if (orow + r < nrows) {
                    if (l16 < 8) el[(size_t)(orow + r) * 8 + l16] = acce[r];
                    else         er[(size_t)(orow + r) * 8 + (l16 - 8)] = acce[r];
                }
            }
        }
    }
}

// ---- per-dst-node GAT: fused softmax+gather, wave-local LDS exp dedup ---
__global__ __launch_bounds__(256) void gat_node(const int* __restrict__ offs,
                                                const int* __restrict__ deg,
                                                const int* __restrict__ csr_src,
                                                const float* __restrict__ el,
                                                const float* __restrict__ er,
                                                const unsigned* __restrict__ featp,
                                                unsigned* __restrict__ gatb) {
    __shared__ float ws[4][64];
    __shared__ int wss[4][8];
    int w = threadIdx.x >> 6;
    int node = blockIdx.x * 4 + w;
    if (node >= N_NODES) return;
    int lane = threadIdx.x & 63;
    int slot = lane >> 3, hh = lane & 7;
    int j = slot;  // head for gather phase
    int beg = offs[node];
    int pend = beg + deg[node];
    float ern = er[node * H + hh];
    float dsum = 0.f, accx = 0.f, accy = 0.f;
    for (int p0 = beg; p0 < pend; p0 += 8) {
        int rem = pend - p0;
        if (rem > 8) rem = 8;
        if (slot < rem) {
            int s = csr_src[p0 + slot];
            float v = el[s * H + hh] + ern;
            v = fmaxf(v, NEG * v);
            ws[w][lane] = __expf(v);
            if (hh == 0) wss[w][slot] = s;
        }
        __builtin_amdgcn_wave_barrier();
        if (rem == 8) {
#pragma unroll
            for (int k = 0; k < 8; ++k) {
                int s = wss[w][k];
                float wk = ws[w][k * 8 + j];
                unsigned q = featp[(size_t)s * 64 + lane];
                dsum += wk;
                accx += wk * plo(q);
                accy += wk * phi(q);
            }
        } else {
            for (int k = 0; k < rem; ++k) {
                int s = wss[w][k];
                float wk = ws[w][k * 8 + j];
                unsigned q = featp[(size_t)s * 64 + lane];
                dsum += wk;
                accx += wk * plo(q);
                accy += wk * phi(q);
            }
        }
        __builtin_amdgcn_wave_barrier();
    }
    float invd = dsum > 0.f ? 1.f / dsum : 0.f;
    gatb[(size_t)node * 64 + lane] = packbf(accx * invd, accy * invd);
}

// ---- BN stats + last-block coef emit ------------------------------------
__global__ __launch_bounds__(256) void bn_stats(const unsigned* __restrict__ xb,
                                                float* __restrict__ sums,
                                                int* __restrict__ cnt,
                                                const float* __restrict__ g,
                                                const float* __restrict__ be,
                                                float* __restrict__ coef, int nrows) {
    int cp = threadIdx.x & 63;   // col pair
    int rr = threadIdx.x >> 6;   // 0..3
    float s0 = 0.f, q0 = 0.f, s1 = 0.f, q1 = 0.f;
    for (int r = blockIdx.x * 4 + rr; r < nrows; r += gridDim.x * 4) {
        unsigned u = xb[(size_t)r * 64 + cp];
        float a = plo(u), b = phi(u);
        s0 += a; q0 += a * a;
        s1 += b; q1 += b * b;
    }
    __shared__ float red[4][256];
    red[0][threadIdx.x] = s0;
    red[1][threadIdx.x] = q0;
    red[2][threadIdx.x] = s1;
    red[3][threadIdx.x] = q1;
    __syncthreads();
    if (rr == 0) {
        int c0 = cp * 2, c1 = c0 + 1;
        float ts0 = red[0][cp] + red[0][cp + 64] + red[0][cp + 128] + red[0][cp + 192];
        float tq0 = red[1][cp] + red[1][cp + 64] + red[1][cp + 128] + red[1][cp + 192];
        float ts1 = red[2][cp] + red[2][cp + 64] + red[2][cp + 128] + red[2][cp + 192];
        float tq1 = red[3][cp] + red[3][cp + 64] + red[3][cp + 128] + red[3][cp + 192];
        atomicAdd(&sums[c0], ts0);
        atomicAdd(&sums[128 + c0], tq0);
        atomicAdd(&sums[c1], ts1);
        atomicAdd(&sums[128 + c1], tq1);
    }
    __threadfence();
    __shared__ int last;
    __syncthreads();
    if (threadIdx.x == 0) last = (atomicAdd(cnt, 1) == (int)gridDim.x - 1);
    __syncthreads();
    if (last && threadIdx.x < 128) {
        int c = threadIdx.x;
        float s = atomicAdd(&sums[c], 0.f);        // device-coherent read
        float q = atomicAdd(&sums[128 + c], 0.f);
        float invN = 1.0f / (float)nrows;
        float mu = s * invN;
        float rs = rsqrtf(q * invN - mu * mu + EPS);
        float a = rs * g[c];
        coef[c] = a;
        coef[128 + c] = be[c] - mu * a;
    }
}

// ---- fused epilogue: bn1+relu + recompute h1 + residual + sum-pool ------
__global__ __launch_bounds__(256) void bn_pool(const unsigned* __restrict__ gat0p,
                                               const unsigned* __restrict__ gat1p,
                                               const float* __restrict__ coef0,
                                               const float* __restrict__ coef1,
                                               const int* __restrict__ gid,
                                               float* __restrict__ pooled) {
    int cp = threadIdx.x & 63;
    int rr = threadIdx.x >> 6;
    int c0 = cp * 2, c1 = c0 + 1;
    float a00 = coef0[c0], a01 = coef0[c1], b00 = coef0[128 + c0], b01 = coef0[128 + c1];
    float a10 = coef1[c0], a11 = coef1[c1], b10 = coef1[128 + c0], b11 = coef1[128 + c1];
    int r0 = blockIdx.x * 512;
    int rend = r0 + 512 < N_NODES ? r0 + 512 : N_NODES;
    int r = r0 + rr;
    if (r >= rend) return;
    float acc0 = 0.f, acc1 = 0.f;
    int cur = gid[r];
    for (; r < rend; r += 4) {
        int gg = gid[r];
        if (gg != cur) {
            atomicAdd(&pooled[cur * HD + c0], acc0);
            atomicAdd(&pooled[cur * HD + c1], acc1);
            acc0 = acc1 = 0.f;
            cur = gg;
        }
        unsigned u1 = gat1p[(size_t)r * 64 + cp];
        unsigned u0 = gat0p[(size_t)r * 64 + cp];
        float z0 = fmaf(plo(u1), a10, b10);
        float z1 = fmaf(phi(u1), a11, b11);
        float h0 = fmaf(plo(u0), a00, b00);
        float h1v = fmaf(phi(u0), a01, b01);
        z0 = z0 > 0.f ? z0 : 0.f;
        z1 = z1 > 0.f ? z1 : 0.f;
        h0 = h0 > 0.f ? h0 : 0.f;
        h1v = h1v > 0.f ? h1v : 0.f;
        acc0 += z0 + h0;
        acc1 += z1 + h1v;
    }
    atomicAdd(&pooled[cur * HD + c0], acc0);
    atomicAdd(&pooled[cur * HD + c1], acc1);
}

// ---- masked prediction head ---------------------------------------------
__global__ void pred_kernel(const float* __restrict__ pooled, const float* __restrict__ W,
                            const float* __restrict__ b, const float* __restrict__ mask,
                            float* __restrict__ out) {
    int t = blockIdx.x * blockDim.x + threadIdx.x;
    if (t >= G_GRAPHS * OUT_DIM) return;
    int g = t >> 6, o = t & 63;
    float acc = b[o];
#pragma unroll 4
    for (int c = 0; c < HD; ++c) {
        float m = mask[o * HD + c] > 0.5f ? 1.f : 0.f;
        acc += pooled[g * HD + c] * W[o * HD + c] * m;
    }
    out[t] = acc;
}

extern "C" void kernel_launch(void* const* d_in, const int* in_sizes, int n_in,
                              void* d_out, int out_size, void* d_ws, size_t ws_size,
                              hipStream_t stream) {
    const float* h   = (const float*)d_in[0];
    const int*   src = (const int*)d_in[1];
    const int*   dst = (const int*)d_in[2];
    const int*   gid = (const int*)d_in[3];
    const float* W0  = (const float*)d_in[4];
    const float* al0 = (const float*)d_in[5];
    const float* ar0 = (const float*)d_in[6];
    // d_in[7] = b0 — BN shift-invariance: bias cancels exactly
    const float* g0  = (const float*)d_in[8];
    const float* be0 = (const float*)d_in[9];
    const float* W1  = (const float*)d_in[10];
    const float* al1 = (const float*)d_in[11];
    const float* ar1 = (const float*)d_in[12];
    // d_in[13] = b1 — cancels
    const float* g1  = (const float*)d_in[14];
    const float* be1 = (const float*)d_in[15];
    const float* pW  = (const float*)d_in[16];
    const float* pb  = (const float*)d_in[17];
    const float* msk = (const float*)d_in[18];
    float* out = (float*)d_out;

    // workspace layout (4B units)
    unsigned* gat0p = (unsigned*)d_ws;                              // [N,64] bf16 pairs
    unsigned* gat1p = gat0p + (size_t)N_NODES * 64;                 // [N,64] bf16 pairs
    unsigned short* featb = (unsigned short*)(gat1p + (size_t)N_NODES * 64); // [N,128] bf16
    float* el   = (float*)(featb + (size_t)N_NODES * HD);           // [N,8]
    float* er   = el + (size_t)N_NODES * H;                         // [N,8]
    int*   offs = (int*)(er + (size_t)N_NODES * H);                 // [N]
    int*   deg  = offs + N_NODES;                                   // [N]
    int*   csr_src = deg + N_NODES;                                 // [E]
    int*   bucketCnt = csr_src + N_EDGES;                           // [256]
    int*   blksum = bucketCnt + 256;                                // [128]
    int*   blkoff = blksum + 128;                                   // [128]
    int*   cnts   = blkoff + 128;                                   // [8]
    float* sums0  = (float*)(cnts + 8);                             // [256]
    float* sums1  = sums0 + 256;                                    // [256]
    float* coef0  = sums1 + 256;                                    // [256]
    float* coef1  = coef0 + 256;                                    // [256]
    float* pooled = coef1 + 256;                                    // [128,128]
    unsigned short* wt0 = (unsigned short*)(pooled + G_GRAPHS * HD);// [128,128] bf16
    unsigned short* wt1 = wt0 + HD * HD;                            // [128,128] bf16
    unsigned short* alr0 = wt1 + HD * HD;                           // [16,128] bf16
    unsigned short* alr1 = alr0 + 16 * HD;                          // [16,128] bf16
    // packed pairs aliased over gat1p (8.0 MB < 25.6 MB; dead before L1 gat)
    int* pairs = (int*)gat1p;

    const int TB = 256;
    dim3 blk(TB);
    int bsc_blocks  = (N_EDGES + 4095) / 4096;
    int node_blocks = (N_NODES + 3) / 4;
    int bnp_blocks  = (N_NODES + 511) / 512;

    // ---------------- CSR build + init + weight convert ----------------
    init_all<<<64, blk, 0, stream>>>(bucketCnt, pooled, sums0, cnts, W0, W1, wt0, wt1,
                                     al0, ar0, al1, ar1, alr0, alr1);
    bucket_scatter<<<bsc_blocks, blk, 0, stream>>>(src, dst, bucketCnt, pairs);
    bucket_count<<<NBUCK, blk, 0, stream>>>(bucketCnt, pairs, deg);
    scan1<<<SCAN_BLOCKS, blk, 0, stream>>>(deg, offs, blksum);
    scan2<<<1, 128, 0, stream>>>(blksum, blkoff);
    scan3<<<SCAN_BLOCKS, blk, 0, stream>>>(offs, blkoff);
    bucket_place<<<NBUCK, blk, 0, stream>>>(bucketCnt, pairs, offs, csr_src);

    // ---------------- layer 0 ----------------
    gemm_mfma<0><<<GEMM_GRID, blk, 0, stream>>>(h, wt0, alr0, nullptr, featb, el, er, N_NODES);
    gat_node<<<node_blocks, blk, 0, stream>>>(offs, deg, csr_src, el, er,
                                              (const unsigned*)featb, gat0p);
    bn_stats<<<512, blk, 0, stream>>>(gat0p, sums0, &cnts[0], g0, be0, coef0, N_NODES);

    // ---------------- layer 1 (BN0+ReLU fused into GEMM staging) --------
    gemm_mfma<2><<<GEMM_GRID, blk, 0, stream>>>(gat0p, wt1, alr1, coef0, featb, el, er, N_NODES);
    gat_node<<<node_blocks, blk, 0, stream>>>(offs, deg, csr_src, el, er,
                                              (const unsigned*)featb, gat1p);
    bn_stats<<<512, blk, 0, stream>>>(gat1p, sums1, &cnts[1], g1, be1, coef1, N_NODES);

    // ---------------- fused epilogue + head ----------------
    bn_pool<<<bnp_blocks, blk, 0, stream>>>(gat0p, gat1p, coef0, coef1, gid, pooled);
    pred_kernel<<<(G_GRAPHS * OUT_DIM + TB - 1) / TB, blk, 0, stream>>>(pooled, pW, pb, msk, out);
}